// Round 9
// baseline (789.490 us; speedup 1.0000x reference)
//
#include <hip/hip_runtime.h>
#include <hip/hip_bf16.h>

#define DI __device__ __forceinline__

typedef __attribute__((ext_vector_type(8))) short bf16x8;
typedef __attribute__((ext_vector_type(4))) float f32x4;

namespace {
constexpr int B_ = 2048, J_ = 17, C_ = 480, K_ = 3, TOK_ = 64, CH_ = 960, H_ = 6, HD_ = 80;
constexpr int C3_ = 3 * C_;            // 1440
constexpr float EPSF = 1e-5f;
}

// branch-free tanh-form GELU: x * sigmoid(2*sqrt(2/pi)*(x + 0.044715 x^3))
DI float gelu_f(float x) {
  const float kA2 = 2.f * 0.7978845608028654f;
  const float kB2 = 2.f * 0.7978845608028654f * 0.044715f;
  const float z = fmaf(-kB2 * x, x * x, -kA2 * x);   // -(2a x + 2b x^3)
  return x / (1.f + __expf(z));
}
DI float b2f(__hip_bfloat16 v) { return __bfloat162float(v); }
DI __hip_bfloat16 f2b(float v) { return __float2bfloat16(v); }
DI float s2f(short s) { return __uint_as_float(((unsigned)(unsigned short)s) << 16); }

DI void gl16(const void* g, void* l) {
  __builtin_amdgcn_global_load_lds(
      (const __attribute__((address_space(1))) unsigned int*)g,
      (__attribute__((address_space(3))) unsigned int*)l, 16, 0, 0);
}

// ---------------- all weights fp32 -> bf16, one kernel (dst arena contiguous) ----------------
__global__ __launch_bounds__(256) void cvt_all_kernel(
    const float* __restrict__ s0, const float* __restrict__ s1,
    const float* __restrict__ s2, const float* __restrict__ s3,
    const float* __restrict__ s4, const float* __restrict__ s5,
    __hip_bfloat16* __restrict__ d) {
  constexpr int SG = C3_ * C_;                 // 691200
  constexpr int O1 = SG, O2 = 2 * SG, O3 = 3 * SG;
  constexpr int O4 = O3 + C_ * C_;             // +230400
  constexpr int O5 = O4 + CH_ * C_;            // +460800
  const int i = (blockIdx.x * 256 + threadIdx.x) * 4;
  const float* s; int off;
  if      (i < O1) { s = s0; off = i; }
  else if (i < O2) { s = s1; off = i - O1; }
  else if (i < O3) { s = s2; off = i - O2; }
  else if (i < O4) { s = s3; off = i - O3; }
  else if (i < O5) { s = s4; off = i - O4; }
  else             { s = s5; off = i - O5; }
  const float4 v = *reinterpret_cast<const float4*>(s + off);
  union { ushort4 u; __hip_bfloat16 h[4]; } o;
  o.h[0] = f2b(v.x); o.h[1] = f2b(v.y); o.h[2] = f2b(v.z); o.h[3] = f2b(v.w);
  *reinterpret_cast<ushort4*>(reinterpret_cast<unsigned short*>(d) + i) = o.u;
}

// ---------------- w2 (J,TOK) -> w2t (TOK,J), f32, tiny one-shot ----------------
__global__ __launch_bounds__(256) void w2t_kernel(const float* __restrict__ w2,
                                                  float* __restrict__ w2t) {
  const int idx = blockIdx.x * 256 + threadIdx.x;
  if (idx < J_ * TOK_) {
    const int t = idx / J_, j = idx % J_;
    w2t[idx] = w2[j * TOK_ + t];
  }
}

// ---------------- LayerNorm over J ----------------
__global__ __launch_bounds__(256) void ln1_kernel(const float* __restrict__ x,
                                                  const float* __restrict__ g,
                                                  const float* __restrict__ bt,
                                                  __hip_bfloat16* __restrict__ xnT, int nBC) {
  const int t = blockIdx.x * 256 + threadIdx.x;
  if (t >= nBC) return;
  const int b = t / C_, c = t % C_;
  const float* xp = x + (size_t)b * J_ * C_ + c;
  float v[J_];
  float s = 0.f;
  #pragma unroll
  for (int j = 0; j < J_; ++j) { v[j] = xp[j * C_]; s += v[j]; }
  const float mu = s * (1.f / J_);
  float sq = 0.f;
  #pragma unroll
  for (int j = 0; j < J_; ++j) { const float d = v[j] - mu; sq += d * d; }
  const float rs = rsqrtf(sq * (1.f / J_) + EPSF);
  __hip_bfloat16* op = xnT + (size_t)b * J_ * C_ + c;
  #pragma unroll
  for (int j = 0; j < J_; ++j) op[j * C_] = f2b((v[j] - mu) * rs * g[j] + bt[j]);
}

// ---------------- LDS-staged GEMM: D[m,n] = sum_k A[m,k]*W[n,k] + bias[n] ----------------
// EPI: 0 = bf16 store, 1 = gelu+bf16, 2 = f32 store of acc+bias+r1+r2 (fused final).
template<int KD, int EPI>
__global__ __launch_bounds__(256) void gemm_lds(const __hip_bfloat16* __restrict__ A,
                                                const __hip_bfloat16* __restrict__ W,
                                                const float* __restrict__ bias,
                                                __hip_bfloat16* __restrict__ Dst, int Ntot,
                                                const __hip_bfloat16* __restrict__ r1,
                                                const __hip_bfloat16* __restrict__ r2,
                                                float* __restrict__ outf) {
  constexpr int NST = (KD + 63) / 64;
  constexpr bool TAIL = (KD % 64) != 0;
  constexpr int ROWB = KD * 2;          // global row stride bytes
  __shared__ __align__(16) char smem[57344];

  const int lane = threadIdx.x & 63;
  const int wid  = threadIdx.x >> 6;
  const int m0g = blockIdx.x * 128;
  const int n0g = blockIdx.y * 96;

  const int srow = lane >> 3;
  const int scbs = ((lane & 7) * 16) ^ ((srow & 7) << 4);  // pre-swizzled source col-byte
  auto stage = [&](int t, int bi) {
    const int kb = t * 128;
    const int ab = bi * 16384;            // A buffer LDS offset
    const int bb = 32768 + bi * 12288;    // B buffer LDS offset
    #pragma unroll
    for (int i = wid; i < 16; i += 4) {   // A: 128 rows
      const int r = i * 8 + srow;
      gl16((const char*)A + (size_t)(m0g + r) * ROWB + kb + scbs, smem + ab + i * 1024);
    }
    #pragma unroll
    for (int i = wid; i < 12; i += 4) {   // B: 96 rows
      const int r = i * 8 + srow;
      gl16((const char*)W + (size_t)(n0g + r) * ROWB + kb + scbs, smem + bb + i * 1024);
    }
  };

  const f32x4 zf = {0.f, 0.f, 0.f, 0.f};
  f32x4 acc[4][3];
  #pragma unroll
  for (int mi = 0; mi < 4; ++mi)
    #pragma unroll
    for (int ni = 0; ni < 3; ++ni) acc[mi][ni] = zf;

  const int rA0 = (wid >> 1) * 64 + (lane & 15);
  const int rB0 = (wid & 1) * 48 + (lane & 15);
  const int swz = (lane & 7) << 4;
  const int kq  = (lane >> 4) * 16;

  stage(0, 0);
  __syncthreads();
  int buf = 0;
  for (int t = 0; t < NST; ++t) {
    if (t + 1 < NST) stage(t + 1, buf ^ 1);
    const int abase = buf * 16384;
    const int bbase = 32768 + buf * 12288;
    const int nks = (TAIL && t == NST - 1) ? 1 : 2;
    for (int ks = 0; ks < nks; ++ks) {
      const int cb = (ks * 64 + kq) ^ swz;
      bf16x8 av[4], bv[3];
      #pragma unroll
      for (int mi = 0; mi < 4; ++mi)
        av[mi] = *reinterpret_cast<const bf16x8*>(smem + abase + (rA0 + mi * 16) * 128 + cb);
      #pragma unroll
      for (int ni = 0; ni < 3; ++ni)
        bv[ni] = *reinterpret_cast<const bf16x8*>(smem + bbase + (rB0 + ni * 16) * 128 + cb);
      #pragma unroll
      for (int mi = 0; mi < 4; ++mi)
        #pragma unroll
        for (int ni = 0; ni < 3; ++ni)
          acc[mi][ni] = __builtin_amdgcn_mfma_f32_16x16x32_bf16(av[mi], bv[ni], acc[mi][ni], 0, 0, 0);
    }
    __syncthreads();
    buf ^= 1;
  }

  const int col0 = n0g + (wid & 1) * 48 + (lane & 15);
  const int r0   = m0g + (wid >> 1) * 64 + ((lane >> 4) << 2);
  #pragma unroll
  for (int ni = 0; ni < 3; ++ni) {
    const int col = col0 + ni * 16;
    const float bvv = bias[col];
    #pragma unroll
    for (int mi = 0; mi < 4; ++mi) {
      #pragma unroll
      for (int r = 0; r < 4; ++r) {
        const size_t idx = (size_t)(r0 + mi * 16 + r) * Ntot + col;
        float v = acc[mi][ni][r] + bvv;
        if (EPI == 1) v = gelu_f(v);
        if (EPI == 2) outf[idx] = v + b2f(r1[idx]) + b2f(r2[idx]);
        else Dst[idx] = f2b(v);
      }
    }
  }
}

// ---------------- attention: 6 heads x (17x17x80) per b, single-pass ----------------
__global__ __launch_bounds__(256) void attn_kernel(const __hip_bfloat16* __restrict__ qkv,
                                                   __hip_bfloat16* __restrict__ o) {
  const int b = blockIdx.x, tid = threadIdx.x;
  __shared__ __hip_bfloat16 sqkv[J_][C3_];
  __shared__ float S[H_][J_][J_];
  {
    const uint4* src = (const uint4*)(qkv + (size_t)b * J_ * C3_);
    uint4* dst = (uint4*)&sqkv[0][0];
    for (int i = tid; i < 3060; i += 256) dst[i] = src[i];
  }
  __syncthreads();
  for (int i = tid; i < H_ * J_ * J_; i += 256) {
    const int h = i / (J_ * J_), r = i % (J_ * J_), qj = r / J_, kj = r % J_;
    const bf16x8* qp = (const bf16x8*)&sqkv[qj][h * HD_];
    const bf16x8* kp = (const bf16x8*)&sqkv[kj][C_ + h * HD_];
    float acc = 0.f;
    #pragma unroll
    for (int d8 = 0; d8 < HD_ / 8; ++d8) {
      const bf16x8 qv = qp[d8], kv = kp[d8];
      #pragma unroll
      for (int t = 0; t < 8; ++t) acc += s2f(qv[t]) * s2f(kv[t]);
    }
    S[h][qj][kj] = acc * 0.11180339887498949f;   // 80^-0.5
  }
  __syncthreads();
  if (tid < H_ * J_) {
    const int h = tid / J_, qj = tid % J_;
    float* row = S[h][qj];
    float m = row[0];
    #pragma unroll
    for (int kk = 1; kk < J_; ++kk) m = fmaxf(m, row[kk]);
    float s = 0.f;
    #pragma unroll
    for (int kk = 0; kk < J_; ++kk) { const float e = __expf(row[kk] - m); row[kk] = e; s += e; }
    const float inv = 1.f / s;
    #pragma unroll
    for (int kk = 0; kk < J_; ++kk) row[kk] *= inv;
  }
  __syncthreads();
  __hip_bfloat16* ob = o + (size_t)b * J_ * C_;
  for (int i = tid; i < J_ * C_; i += 256) {
    const int qj = i / C_, c = i % C_;
    const int h = c / HD_;
    const float* srow = S[h][qj];
    float acc = 0.f;
    #pragma unroll
    for (int kk = 0; kk < J_; ++kk) acc += srow[kk] * b2f(sqkv[kk][2 * C_ + c]);
    ob[i] = f2b(acc);
  }
}

// ---------------- gcn adjacency contraction ----------------
__global__ __launch_bounds__(512) void gcn_contract_kernel(const __hip_bfloat16* __restrict__ y,
                                                           const float* __restrict__ adj,
                                                           __hip_bfloat16* __restrict__ g) {
  const int b = blockIdx.x, tid = threadIdx.x;
  __shared__ float adjl[K_ * J_ * J_];
  for (int i = tid; i < K_ * J_ * J_; i += 512) adjl[i] = adj[i];
  __syncthreads();
  const int c = tid;
  if (c < C_) {
    float yv[K_][J_];
    const __hip_bfloat16* yb = y + (size_t)b * J_ * C3_ + c;
    #pragma unroll
    for (int k = 0; k < K_; ++k)
      #pragma unroll
      for (int v = 0; v < J_; ++v)
        yv[k][v] = b2f(yb[(size_t)v * C3_ + k * C_]);
    __hip_bfloat16* gp = g + (size_t)b * J_ * C_ + c;
    #pragma unroll
    for (int w = 0; w < J_; ++w) {
      float acc = 0.f;
      #pragma unroll
      for (int k = 0; k < K_; ++k)
        #pragma unroll
        for (int v = 0; v < J_; ++v)
          acc += yv[k][v] * adjl[(k * J_ + v) * J_ + w];
      gp[w * C_] = f2b(acc);
    }
  }
}

// ---------------- dwconv7 + GroupNorm(16) + GELU + token-MLP (fused, register-only) ----------
// Token-MLP t-loop FULLY unrolled so every weight offset is a compile-time constant off a
// uniform kernel-arg pointer -> s_load with immediate offset (scalar path, zero VALU addr math).
__global__ __launch_bounds__(512) void dwmlp_kernel(const __hip_bfloat16* __restrict__ xnT,
    const float* __restrict__ dww, const float* __restrict__ dwb,
    const float* __restrict__ gg, const float* __restrict__ gb,
    const float* __restrict__ w1, const float* __restrict__ b1,
    const float* __restrict__ w2t, const float* __restrict__ b2,
    __hip_bfloat16* __restrict__ mjem) {
  const int b = blockIdx.x, tid = threadIdx.x;
  __shared__ __hip_bfloat16 xl[J_][C_];
  __shared__ float gstat[16][2];
  {
    const uint4* src = (const uint4*)(xnT + (size_t)b * J_ * C_);
    uint4* dst = (uint4*)&xl[0][0];
    for (int i = tid; i < 1020; i += 512) dst[i] = src[i];
  }
  if (tid < 32) gstat[tid >> 1][tid & 1] = 0.f;
  __syncthreads();
  const int c = tid;
  float dv[J_];
  if (c < C_) {
    float wv[7];
    #pragma unroll
    for (int t = 0; t < 7; ++t) wv[t] = dww[c * 7 + t];
    const float bias = dwb[c];
    float s = 0.f, sqs = 0.f;
    #pragma unroll
    for (int j = 0; j < J_; ++j) {
      float acc = bias;
      #pragma unroll
      for (int t = 0; t < 7; ++t) {
        const int jj = j - 3 + t;
        if (jj >= 0 && jj < J_) acc += b2f(xl[jj][c]) * wv[t];
      }
      dv[j] = acc; s += acc; sqs += acc * acc;
    }
    atomicAdd(&gstat[c / 30][0], s);
    atomicAdd(&gstat[c / 30][1], sqs);
  }
  __syncthreads();
  if (c < C_) {
    const float mu = gstat[c / 30][0] * (1.f / 510.f);
    const float var = gstat[c / 30][1] * (1.f / 510.f) - mu * mu;
    const float rs = rsqrtf(var + EPSF);
    const float sc = gg[c], of = gb[c];
    #pragma unroll
    for (int j = 0; j < J_; ++j) dv[j] = gelu_f((dv[j] - mu) * rs * sc + of);
    // fused token-MLP, FULL unroll: all w1/w2t/b1 offsets compile-time -> scalar loads
    float mj[J_];
    #pragma unroll
    for (int j = 0; j < J_; ++j) mj[j] = b2[j];
    #pragma unroll
    for (int t = 0; t < TOK_; ++t) {
      float acc = b1[t];
      #pragma unroll
      for (int j = 0; j < J_; ++j) acc = fmaf(dv[j], w1[t * J_ + j], acc);
      const float hg = gelu_f(acc);
      #pragma unroll
      for (int j = 0; j < J_; ++j) mj[j] = fmaf(hg, w2t[t * J_ + j], mj[j]);
    }
    __hip_bfloat16* dst = mjem + (size_t)b * J_ * C_ + c;
    #pragma unroll
    for (int j = 0; j < J_; ++j) dst[j * C_] = f2b(mj[j]);
  }
}

// ---------------- fuse: pos-conv + sum + GN + GELU + residual + LN2 ----------------
__global__ __launch_bounds__(512) void fuse_kernel(
    const float* __restrict__ x, const __hip_bfloat16* __restrict__ xnT,
    const __hip_bfloat16* __restrict__ g1o, const __hip_bfloat16* __restrict__ projo,
    const __hip_bfloat16* __restrict__ mjem,
    const float* __restrict__ posw, const float* __restrict__ posb,
    const float* __restrict__ gnfg, const float* __restrict__ gnfb,
    const float* __restrict__ n2g, const float* __restrict__ n2b,
    __hip_bfloat16* __restrict__ resch, __hip_bfloat16* __restrict__ xn2) {
  const int b = blockIdx.x, tid = threadIdx.x;
  __shared__ float xcl[J_][C_];
  __shared__ float gstat[16][2];
  __shared__ float lnst[J_][2];
  if (tid < 32) gstat[tid >> 1][tid & 1] = 0.f;
  __syncthreads();
  const int c = tid;
  float fz[J_];
  if (c < C_) {
    float xnv[J_];
    const __hip_bfloat16* xp = xnT + (size_t)b * J_ * C_ + c;
    #pragma unroll
    for (int j = 0; j < J_; ++j) xnv[j] = b2f(xp[j * C_]);
    float pw[9];
    #pragma unroll
    for (int t = 0; t < 9; ++t) pw[t] = posw[c * 9 + t];
    const float pb = posb[c];
    const __hip_bfloat16* pj = projo + (size_t)b * J_ * C_ + c;
    const __hip_bfloat16* mp = mjem + (size_t)b * J_ * C_ + c;
    const __hip_bfloat16* gp = g1o + (size_t)b * J_ * C_ + c;
    float s = 0.f, sqs = 0.f;
    #pragma unroll
    for (int j = 0; j < J_; ++j) {
      float pos = pb;
      #pragma unroll
      for (int t = 0; t < 9; ++t) {
        const int jj = j - 4 + t;
        if (jj >= 0 && jj < J_) pos += xnv[jj] * pw[t];
      }
      const float f = b2f(pj[j * C_]) + pos + b2f(gp[j * C_]) + b2f(mp[j * C_]);
      fz[j] = f; s += f; sqs += f * f;
    }
    atomicAdd(&gstat[c / 30][0], s);
    atomicAdd(&gstat[c / 30][1], sqs);
  }
  __syncthreads();
  if (c < C_) {
    const float mu = gstat[c / 30][0] * (1.f / 510.f);
    const float var = gstat[c / 30][1] * (1.f / 510.f) - mu * mu;
    const float rs = rsqrtf(var + EPSF);
    const float sc = gnfg[c], of = gnfb[c];
    const float* xr = x + (size_t)b * J_ * C_ + c;
    __hip_bfloat16* rp = resch + (size_t)b * J_ * C_ + c;
    #pragma unroll
    for (int j = 0; j < J_; ++j) {
      const float xcv = xr[j * C_] + gelu_f((fz[j] - mu) * rs * sc + of);
      xcl[j][c] = xcv;
      rp[j * C_] = f2b(xcv);
    }
  }
  __syncthreads();
  const int wid = tid >> 6, lane = tid & 63;
  for (int j = wid; j < J_; j += 8) {
    float ls = 0.f, lq = 0.f;
    for (int cc = lane; cc < C_; cc += 64) { const float v = xcl[j][cc]; ls += v; lq += v * v; }
    #pragma unroll
    for (int off = 32; off > 0; off >>= 1) { ls += __shfl_xor(ls, off); lq += __shfl_xor(lq, off); }
    if (lane == 0) {
      const float mu = ls * (1.f / C_);
      const float var = lq * (1.f / C_) - mu * mu;
      lnst[j][0] = mu; lnst[j][1] = rsqrtf(var + EPSF);
    }
  }
  __syncthreads();
  if (c < C_) {
    const float sc = n2g[c], of = n2b[c];
    __hip_bfloat16* xp2 = xn2 + (size_t)b * J_ * C_ + c;
    #pragma unroll
    for (int j = 0; j < J_; ++j)
      xp2[j * C_] = f2b((xcl[j][c] - lnst[j][0]) * lnst[j][1] * sc + of);
  }
}

extern "C" void kernel_launch(void* const* d_in, const int* in_sizes, int n_in,
                              void* d_out, int out_size, void* d_ws, size_t ws_size,
                              hipStream_t stream) {
  const float* x      = (const float*)d_in[0];
  const float* adj    = (const float*)d_in[1];
  const float* n1g    = (const float*)d_in[2];
  const float* n1b    = (const float*)d_in[3];
  const float* gcn1_w = (const float*)d_in[4];
  const float* gcn1_b = (const float*)d_in[5];
  const float* dw_w   = (const float*)d_in[6];
  const float* dw_b   = (const float*)d_in[7];
  const float* dwgn_g = (const float*)d_in[8];
  const float* dwgn_b = (const float*)d_in[9];
  const float* m1w1   = (const float*)d_in[10];
  const float* m1b1   = (const float*)d_in[11];
  const float* m1w2   = (const float*)d_in[12];
  const float* m1b2   = (const float*)d_in[13];
  const float* qkv_w  = (const float*)d_in[14];
  const float* qkv_b  = (const float*)d_in[15];
  const float* proj_w = (const float*)d_in[16];
  const float* proj_b = (const float*)d_in[17];
  const float* pos_w  = (const float*)d_in[18];
  const float* pos_b  = (const float*)d_in[19];
  const float* gnf_g  = (const float*)d_in[20];
  const float* gnf_b  = (const float*)d_in[21];
  const float* n2g    = (const float*)d_in[22];
  const float* n2b    = (const float*)d_in[23];
  const float* gcn2_w = (const float*)d_in[24];
  const float* gcn2_b = (const float*)d_in[25];
  const float* m2w1   = (const float*)d_in[26];
  const float* m2b1   = (const float*)d_in[27];
  const float* m2w2   = (const float*)d_in[28];
  const float* m2b2   = (const float*)d_in[29];
  float* out = (float*)d_out;
  char* ws = (char*)d_ws;
  (void)in_sizes; (void)n_in; (void)out_size;

  auto a256 = [](size_t b) { return (b + 255) & ~(size_t)255; };
  const size_t wbytes = 3 * a256((size_t)C3_ * C_ * 2) + a256((size_t)C_ * C_ * 2) +
                        a256((size_t)CH_ * C_ * 2) + a256((size_t)C_ * CH_ * 2) +
                        a256((size_t)J_ * TOK_ * 4);
  int nch = 16;
  for (int cand : {1, 2, 4, 8, 16}) {
    const size_t Mcb = (size_t)(B_ / cand) * J_;
    const size_t fp = wbytes + a256(Mcb * C3_ * 2) + 6 * a256(Mcb * C_ * 2);
    if (fp <= ws_size) { nch = cand; break; }
  }
  const int Bc = B_ / nch;
  const int Mc = Bc * J_;

  size_t off = 0;
  auto alloc = [&](size_t bytes) { char* p = ws + off; off += a256(bytes); return p; };
  // weight arena: 6 contiguous segments in cvt_all ladder order (alloc order matters!)
  __hip_bfloat16* w_qkv = (__hip_bfloat16*)alloc((size_t)C3_ * C_ * 2);
  __hip_bfloat16* w_g1  = (__hip_bfloat16*)alloc((size_t)C3_ * C_ * 2);
  __hip_bfloat16* w_g2  = (__hip_bfloat16*)alloc((size_t)C3_ * C_ * 2);
  __hip_bfloat16* w_pr  = (__hip_bfloat16*)alloc((size_t)C_ * C_ * 2);
  __hip_bfloat16* w_21  = (__hip_bfloat16*)alloc((size_t)CH_ * C_ * 2);
  __hip_bfloat16* w_22  = (__hip_bfloat16*)alloc((size_t)C_ * CH_ * 2);
  float*          w2t   = (float*)alloc((size_t)J_ * TOK_ * 4);
  __hip_bfloat16* BIG   = (__hip_bfloat16*)alloc((size_t)Mc * C3_ * 2);  // qkv -> y1 -> y2 -> hbuf
  __hip_bfloat16* xnT   = (__hip_bfloat16*)alloc((size_t)Mc * C_ * 2);
  __hip_bfloat16* attno = (__hip_bfloat16*)alloc((size_t)Mc * C_ * 2);   // -> xn2
  __hip_bfloat16* projo = (__hip_bfloat16*)alloc((size_t)Mc * C_ * 2);
  __hip_bfloat16* mjem  = (__hip_bfloat16*)alloc((size_t)Mc * C_ * 2);
  __hip_bfloat16* g1o   = (__hip_bfloat16*)alloc((size_t)Mc * C_ * 2);   // -> g2o
  __hip_bfloat16* resch = (__hip_bfloat16*)alloc((size_t)Mc * C_ * 2);
  __hip_bfloat16* xn2   = attno;
  __hip_bfloat16* g2o   = g1o;
  __hip_bfloat16* hbuf  = BIG;

  cvt_all_kernel<<<3150, 256, 0, stream>>>(qkv_w, gcn1_w, gcn2_w, proj_w, m2w1, m2w2, w_qkv);
  w2t_kernel<<<(J_ * TOK_ + 255) / 256, 256, 0, stream>>>(m1w2, w2t);

  for (int ci = 0; ci < nch; ++ci) {
    const float* xc = x + (size_t)ci * Bc * J_ * C_;
    float* outc = out + (size_t)ci * Bc * J_ * C_;
    ln1_kernel<<<(Bc * C_ + 255) / 256, 256, 0, stream>>>(xc, n1g, n1b, xnT, Bc * C_);
    gemm_lds<C_, 0><<<dim3(Mc / 128, C3_ / 96), 256, 0, stream>>>(xnT, w_qkv, qkv_b, BIG, C3_, nullptr, nullptr, nullptr);
    attn_kernel<<<Bc, 256, 0, stream>>>(BIG, attno);
    gemm_lds<C_, 0><<<dim3(Mc / 128, C3_ / 96), 256, 0, stream>>>(xnT, w_g1, gcn1_b, BIG, C3_, nullptr, nullptr, nullptr);
    gcn_contract_kernel<<<Bc, 512, 0, stream>>>(BIG, adj, g1o);
    gemm_lds<C_, 0><<<dim3(Mc / 128, C_ / 96), 256, 0, stream>>>(attno, w_pr, proj_b, projo, C_, nullptr, nullptr, nullptr);
    dwmlp_kernel<<<Bc, 512, 0, stream>>>(xnT, dw_w, dw_b, dwgn_g, dwgn_b, m1w1, m1b1, w2t, m1b2, mjem);
    fuse_kernel<<<Bc, 512, 0, stream>>>(xc, xnT, g1o, projo, mjem, pos_w, pos_b,
                                        gnf_g, gnf_b, n2g, n2b, resch, xn2);
    gemm_lds<C_, 0><<<dim3(Mc / 128, C3_ / 96), 256, 0, stream>>>(xn2, w_g2, gcn2_b, BIG, C3_, nullptr, nullptr, nullptr);
    gcn_contract_kernel<<<Bc, 512, 0, stream>>>(BIG, adj, g2o);
    gemm_lds<C_, 1><<<dim3(Mc / 128, CH_ / 96), 256, 0, stream>>>(xn2, w_21, m2b1, hbuf, CH_, nullptr, nullptr, nullptr);
    gemm_lds<CH_, 2><<<dim3(Mc / 128, C_ / 96), 256, 0, stream>>>(hbuf, w_22, m2b2, nullptr, C_, resch, g2o, outc);
  }
}

// Round 10
// 738.439 us; speedup vs baseline: 1.0691x; 1.0691x over previous
//
#include <hip/hip_runtime.h>
#include <hip/hip_bf16.h>

#define DI __device__ __forceinline__

typedef __attribute__((ext_vector_type(8))) short bf16x8;
typedef __attribute__((ext_vector_type(4))) float f32x4;

namespace {
constexpr int B_ = 2048, J_ = 17, C_ = 480, K_ = 3, TOK_ = 64, CH_ = 960, H_ = 6, HD_ = 80;
constexpr int C3_ = 3 * C_;            // 1440
constexpr float EPSF = 1e-5f;
}

// branch-free tanh-form GELU: x * sigmoid(2*sqrt(2/pi)*(x + 0.044715 x^3))
DI float gelu_f(float x) {
  const float kA2 = 2.f * 0.7978845608028654f;
  const float kB2 = 2.f * 0.7978845608028654f * 0.044715f;
  const float z = fmaf(-kB2 * x, x * x, -kA2 * x);   // -(2a x + 2b x^3)
  return x / (1.f + __expf(z));
}
DI float b2f(__hip_bfloat16 v) { return __bfloat162float(v); }
DI __hip_bfloat16 f2b(float v) { return __float2bfloat16(v); }
DI float s2f(short s) { return __uint_as_float(((unsigned)(unsigned short)s) << 16); }
DI unsigned pk2(float a, float b) {
  union { unsigned u; __hip_bfloat16 h[2]; } p;
  p.h[0] = f2b(a); p.h[1] = f2b(b);
  return p.u;
}

DI void gl16(const void* g, void* l) {
  __builtin_amdgcn_global_load_lds(
      (const __attribute__((address_space(1))) unsigned int*)g,
      (__attribute__((address_space(3))) unsigned int*)l, 16, 0, 0);
}

// ---------------- all weights fp32 -> bf16, one kernel (dst arena contiguous) ----------------
__global__ __launch_bounds__(256) void cvt_all_kernel(
    const float* __restrict__ s0, const float* __restrict__ s1,
    const float* __restrict__ s2, const float* __restrict__ s3,
    const float* __restrict__ s4, const float* __restrict__ s5,
    __hip_bfloat16* __restrict__ d) {
  constexpr int SG = C3_ * C_;                 // 691200
  constexpr int O1 = SG, O2 = 2 * SG, O3 = 3 * SG;
  constexpr int O4 = O3 + C_ * C_;             // +230400
  constexpr int O5 = O4 + CH_ * C_;            // +460800
  const int i = (blockIdx.x * 256 + threadIdx.x) * 4;
  const float* s; int off;
  if      (i < O1) { s = s0; off = i; }
  else if (i < O2) { s = s1; off = i - O1; }
  else if (i < O3) { s = s2; off = i - O2; }
  else if (i < O4) { s = s3; off = i - O3; }
  else if (i < O5) { s = s4; off = i - O4; }
  else             { s = s5; off = i - O5; }
  const float4 v = *reinterpret_cast<const float4*>(s + off);
  union { ushort4 u; __hip_bfloat16 h[4]; } o;
  o.h[0] = f2b(v.x); o.h[1] = f2b(v.y); o.h[2] = f2b(v.z); o.h[3] = f2b(v.w);
  *reinterpret_cast<ushort4*>(reinterpret_cast<unsigned short*>(d) + i) = o.u;
}

// ---------------- LayerNorm over J ----------------
__global__ __launch_bounds__(256) void ln1_kernel(const float* __restrict__ x,
                                                  const float* __restrict__ g,
                                                  const float* __restrict__ bt,
                                                  __hip_bfloat16* __restrict__ xnT, int nBC) {
  const int t = blockIdx.x * 256 + threadIdx.x;
  if (t >= nBC) return;
  const int b = t / C_, c = t % C_;
  const float* xp = x + (size_t)b * J_ * C_ + c;
  float v[J_];
  float s = 0.f;
  #pragma unroll
  for (int j = 0; j < J_; ++j) { v[j] = xp[j * C_]; s += v[j]; }
  const float mu = s * (1.f / J_);
  float sq = 0.f;
  #pragma unroll
  for (int j = 0; j < J_; ++j) { const float d = v[j] - mu; sq += d * d; }
  const float rs = rsqrtf(sq * (1.f / J_) + EPSF);
  __hip_bfloat16* op = xnT + (size_t)b * J_ * C_ + c;
  #pragma unroll
  for (int j = 0; j < J_; ++j) op[j * C_] = f2b((v[j] - mu) * rs * g[j] + bt[j]);
}

// ---------------- LDS-staged GEMM: D[m,n] = sum_k A[m,k]*W[n,k] + bias[n] ----------------
// EPI: 0 = bf16 store, 1 = gelu+bf16, 2 = f32 store of acc+bias+r1+r2 (fused final).
template<int KD, int EPI>
__global__ __launch_bounds__(256) void gemm_lds(const __hip_bfloat16* __restrict__ A,
                                                const __hip_bfloat16* __restrict__ W,
                                                const float* __restrict__ bias,
                                                __hip_bfloat16* __restrict__ Dst, int Ntot,
                                                const __hip_bfloat16* __restrict__ r1,
                                                const __hip_bfloat16* __restrict__ r2,
                                                float* __restrict__ outf) {
  constexpr int NST = (KD + 63) / 64;
  constexpr bool TAIL = (KD % 64) != 0;
  constexpr int ROWB = KD * 2;          // global row stride bytes
  __shared__ __align__(16) char smem[57344];

  const int lane = threadIdx.x & 63;
  const int wid  = threadIdx.x >> 6;
  const int m0g = blockIdx.x * 128;
  const int n0g = blockIdx.y * 96;

  const int srow = lane >> 3;
  const int scbs = ((lane & 7) * 16) ^ ((srow & 7) << 4);  // pre-swizzled source col-byte
  auto stage = [&](int t, int bi) {
    const int kb = t * 128;
    const int ab = bi * 16384;            // A buffer LDS offset
    const int bb = 32768 + bi * 12288;    // B buffer LDS offset
    #pragma unroll
    for (int i = wid; i < 16; i += 4) {   // A: 128 rows
      const int r = i * 8 + srow;
      gl16((const char*)A + (size_t)(m0g + r) * ROWB + kb + scbs, smem + ab + i * 1024);
    }
    #pragma unroll
    for (int i = wid; i < 12; i += 4) {   // B: 96 rows
      const int r = i * 8 + srow;
      gl16((const char*)W + (size_t)(n0g + r) * ROWB + kb + scbs, smem + bb + i * 1024);
    }
  };

  const f32x4 zf = {0.f, 0.f, 0.f, 0.f};
  f32x4 acc[4][3];
  #pragma unroll
  for (int mi = 0; mi < 4; ++mi)
    #pragma unroll
    for (int ni = 0; ni < 3; ++ni) acc[mi][ni] = zf;

  const int rA0 = (wid >> 1) * 64 + (lane & 15);
  const int rB0 = (wid & 1) * 48 + (lane & 15);
  const int swz = (lane & 7) << 4;
  const int kq  = (lane >> 4) * 16;

  stage(0, 0);
  __syncthreads();
  int buf = 0;
  for (int t = 0; t < NST; ++t) {
    if (t + 1 < NST) stage(t + 1, buf ^ 1);
    const int abase = buf * 16384;
    const int bbase = 32768 + buf * 12288;
    const int nks = (TAIL && t == NST - 1) ? 1 : 2;
    for (int ks = 0; ks < nks; ++ks) {
      const int cb = (ks * 64 + kq) ^ swz;
      bf16x8 av[4], bv[3];
      #pragma unroll
      for (int mi = 0; mi < 4; ++mi)
        av[mi] = *reinterpret_cast<const bf16x8*>(smem + abase + (rA0 + mi * 16) * 128 + cb);
      #pragma unroll
      for (int ni = 0; ni < 3; ++ni)
        bv[ni] = *reinterpret_cast<const bf16x8*>(smem + bbase + (rB0 + ni * 16) * 128 + cb);
      #pragma unroll
      for (int mi = 0; mi < 4; ++mi)
        #pragma unroll
        for (int ni = 0; ni < 3; ++ni)
          acc[mi][ni] = __builtin_amdgcn_mfma_f32_16x16x32_bf16(av[mi], bv[ni], acc[mi][ni], 0, 0, 0);
    }
    __syncthreads();
    buf ^= 1;
  }

  const int col0 = n0g + (wid & 1) * 48 + (lane & 15);
  const int r0   = m0g + (wid >> 1) * 64 + ((lane >> 4) << 2);
  #pragma unroll
  for (int ni = 0; ni < 3; ++ni) {
    const int col = col0 + ni * 16;
    const float bvv = bias[col];
    #pragma unroll
    for (int mi = 0; mi < 4; ++mi) {
      #pragma unroll
      for (int r = 0; r < 4; ++r) {
        const size_t idx = (size_t)(r0 + mi * 16 + r) * Ntot + col;
        float v = acc[mi][ni][r] + bvv;
        if (EPI == 1) v = gelu_f(v);
        if (EPI == 2) outf[idx] = v + b2f(r1[idx]) + b2f(r2[idx]);
        else Dst[idx] = f2b(v);
      }
    }
  }
}

// ---------------- attention: 6 heads x (17x17x80) per b, single-pass ----------------
__global__ __launch_bounds__(256) void attn_kernel(const __hip_bfloat16* __restrict__ qkv,
                                                   __hip_bfloat16* __restrict__ o) {
  const int b = blockIdx.x, tid = threadIdx.x;
  __shared__ __hip_bfloat16 sqkv[J_][C3_];
  __shared__ float S[H_][J_][J_];
  {
    const uint4* src = (const uint4*)(qkv + (size_t)b * J_ * C3_);
    uint4* dst = (uint4*)&sqkv[0][0];
    for (int i = tid; i < 3060; i += 256) dst[i] = src[i];
  }
  __syncthreads();
  for (int i = tid; i < H_ * J_ * J_; i += 256) {
    const int h = i / (J_ * J_), r = i % (J_ * J_), qj = r / J_, kj = r % J_;
    const bf16x8* qp = (const bf16x8*)&sqkv[qj][h * HD_];
    const bf16x8* kp = (const bf16x8*)&sqkv[kj][C_ + h * HD_];
    float acc = 0.f;
    #pragma unroll
    for (int d8 = 0; d8 < HD_ / 8; ++d8) {
      const bf16x8 qv = qp[d8], kv = kp[d8];
      #pragma unroll
      for (int t = 0; t < 8; ++t) acc += s2f(qv[t]) * s2f(kv[t]);
    }
    S[h][qj][kj] = acc * 0.11180339887498949f;   // 80^-0.5
  }
  __syncthreads();
  if (tid < H_ * J_) {
    const int h = tid / J_, qj = tid % J_;
    float* row = S[h][qj];
    float m = row[0];
    #pragma unroll
    for (int kk = 1; kk < J_; ++kk) m = fmaxf(m, row[kk]);
    float s = 0.f;
    #pragma unroll
    for (int kk = 0; kk < J_; ++kk) { const float e = __expf(row[kk] - m); row[kk] = e; s += e; }
    const float inv = 1.f / s;
    #pragma unroll
    for (int kk = 0; kk < J_; ++kk) row[kk] *= inv;
  }
  __syncthreads();
  __hip_bfloat16* ob = o + (size_t)b * J_ * C_;
  for (int i = tid; i < J_ * C_; i += 256) {
    const int qj = i / C_, c = i % C_;
    const int h = c / HD_;
    const float* srow = S[h][qj];
    float acc = 0.f;
    #pragma unroll
    for (int kk = 0; kk < J_; ++kk) acc += srow[kk] * b2f(sqkv[kk][2 * C_ + c]);
    ob[i] = f2b(acc);
  }
}

// ---------------- gcn adjacency contraction ----------------
__global__ __launch_bounds__(512) void gcn_contract_kernel(const __hip_bfloat16* __restrict__ y,
                                                           const float* __restrict__ adj,
                                                           __hip_bfloat16* __restrict__ g) {
  const int b = blockIdx.x, tid = threadIdx.x;
  __shared__ float adjl[K_ * J_ * J_];
  for (int i = tid; i < K_ * J_ * J_; i += 512) adjl[i] = adj[i];
  __syncthreads();
  const int c = tid;
  if (c < C_) {
    float yv[K_][J_];
    const __hip_bfloat16* yb = y + (size_t)b * J_ * C3_ + c;
    #pragma unroll
    for (int k = 0; k < K_; ++k)
      #pragma unroll
      for (int v = 0; v < J_; ++v)
        yv[k][v] = b2f(yb[(size_t)v * C3_ + k * C_]);
    __hip_bfloat16* gp = g + (size_t)b * J_ * C_ + c;
    #pragma unroll
    for (int w = 0; w < J_; ++w) {
      float acc = 0.f;
      #pragma unroll
      for (int k = 0; k < K_; ++k)
        #pragma unroll
        for (int v = 0; v < J_; ++v)
          acc += yv[k][v] * adjl[(k * J_ + v) * J_ + w];
      gp[w * C_] = f2b(acc);
    }
  }
}

// ---------------- dwconv7 + GroupNorm(16) + GELU + token-MLP via in-block MFMA ----------------
// Phase 1 (thread=channel): dwconv+GN+GELU -> dv[17] -> LDS Dt[c][j] (K-padded 17->32).
// Phase 2 (per-wave GEMMs): H = gelu(W1p @ Dt^T + b1) [64x16 per c-block, in-reg] ->
//   per-wave LDS Hsm -> mjem-block = W2p @ Hsm^T + b2. No barriers inside the loop.
// Row pads (80B / 144B) keep ds_read_b128 16B-aligned and <=2-way banked.
__global__ __launch_bounds__(512) void dwmlp_kernel(const __hip_bfloat16* __restrict__ xnT,
    const float* __restrict__ dww, const float* __restrict__ dwb,
    const float* __restrict__ gg, const float* __restrict__ gb,
    const float* __restrict__ w1, const float* __restrict__ b1,
    const float* __restrict__ w2, const float* __restrict__ b2,
    __hip_bfloat16* __restrict__ mjem) {
  // LDS (bytes): [0,18432) phase1 xl[J][C] bf16 (16320) / phase2 Hsm 8w x 16 x 144B
  //              [18432,56832) Dt 480 x 80B ; [56832,61952) W1p 64 x 80B ; [61952,66560) W2p 32 x 144B
  __shared__ __align__(16) char lds[66560];
  __shared__ float gstat[16][2];
  constexpr int XL = 0, DT = 18432, W1P = 56832, W2P = 61952;
  const int b = blockIdx.x, tid = threadIdx.x;
  const int lane = tid & 63, wid = tid >> 6;

  { // stage xl (1020 uint4)
    const uint4* src = (const uint4*)(xnT + (size_t)b * J_ * C_);
    uint4* dst = (uint4*)(lds + XL);
    for (int i = tid; i < 1020; i += 512) dst[i] = src[i];
  }
  { // stage W1p: 64 rows x 40 elems (17 valid, rest 0)
    __hip_bfloat16* wp = (__hip_bfloat16*)(lds + W1P);
    for (int i = tid; i < 64 * 40; i += 512) {
      const int t = i / 40, j = i % 40;
      wp[i] = (j < J_) ? f2b(w1[t * J_ + j]) : f2b(0.f);
    }
  }
  { // stage W2p: 32 rows x 72 elems (17x64 valid, rest 0)
    __hip_bfloat16* wp = (__hip_bfloat16*)(lds + W2P);
    for (int i = tid; i < 32 * 72; i += 512) {
      const int j = i / 72, t = i % 72;
      wp[i] = (j < J_ && t < TOK_) ? f2b(w2[j * TOK_ + t]) : f2b(0.f);
    }
  }
  if (tid < 32) gstat[tid >> 1][tid & 1] = 0.f;
  __syncthreads();

  const int c = tid;
  float dv[J_];
  if (c < C_) {
    const __hip_bfloat16* xl = (const __hip_bfloat16*)(lds + XL);
    float wv[7];
    #pragma unroll
    for (int t = 0; t < 7; ++t) wv[t] = dww[c * 7 + t];
    const float bias = dwb[c];
    float s = 0.f, sqs = 0.f;
    #pragma unroll
    for (int j = 0; j < J_; ++j) {
      float acc = bias;
      #pragma unroll
      for (int t = 0; t < 7; ++t) {
        const int jj = j - 3 + t;
        if (jj >= 0 && jj < J_) acc += b2f(xl[jj * C_ + c]) * wv[t];
      }
      dv[j] = acc; s += acc; sqs += acc * acc;
    }
    atomicAdd(&gstat[c / 30][0], s);
    atomicAdd(&gstat[c / 30][1], sqs);
  }
  __syncthreads();
  if (c < C_) {
    const float mu = gstat[c / 30][0] * (1.f / 510.f);
    const float var = gstat[c / 30][1] * (1.f / 510.f) - mu * mu;
    const float rs = rsqrtf(var + EPSF);
    const float sc = gg[c], of = gb[c];
    #pragma unroll
    for (int j = 0; j < J_; ++j) dv[j] = gelu_f((dv[j] - mu) * rs * sc + of);
    // write Dt row c: cols 0..16 = dv, 17..31 = 0
    unsigned* rp = (unsigned*)(lds + DT + c * 80);
    #pragma unroll
    for (int p = 0; p < 8; ++p) rp[p] = pk2(dv[2 * p], dv[2 * p + 1]);
    rp[8] = pk2(dv[16], 0.f);
    #pragma unroll
    for (int p = 9; p < 16; ++p) rp[p] = 0u;
  }
  __syncthreads();

  // ---- per-wave MFMA phase (xl region now reused as Hsm) ----
  const int lr = lane & 15, kc = lane >> 4;
  bf16x8 a1[4];
  #pragma unroll
  for (int mi = 0; mi < 4; ++mi)
    a1[mi] = *(const bf16x8*)(lds + W1P + (lr + mi * 16) * 80 + kc * 16);
  bf16x8 a2[2][2];
  #pragma unroll
  for (int mi = 0; mi < 2; ++mi)
    #pragma unroll
    for (int kk = 0; kk < 2; ++kk)
      a2[mi][kk] = *(const bf16x8*)(lds + W2P + (lr + mi * 16) * 144 + kk * 64 + kc * 16);
  float b1v[4][4];
  #pragma unroll
  for (int mi = 0; mi < 4; ++mi)
    #pragma unroll
    for (int r = 0; r < 4; ++r) b1v[mi][r] = b1[mi * 16 + kc * 4 + r];
  float b2v[4];
  #pragma unroll
  for (int r = 0; r < 4; ++r) b2v[r] = b2[kc * 4 + r];
  const float b2v16 = b2[16];

  char* hs = lds + XL + wid * 2304;         // private 16 x 144B per wave
  const f32x4 zf4 = {0.f, 0.f, 0.f, 0.f};
  for (int cb = wid; cb < 30; cb += 8) {
    const int c0 = cb * 16;
    const bf16x8 bf = *(const bf16x8*)(lds + DT + (c0 + lr) * 80 + kc * 16);
    f32x4 acc1[4];
    #pragma unroll
    for (int mi = 0; mi < 4; ++mi)
      acc1[mi] = __builtin_amdgcn_mfma_f32_16x16x32_bf16(a1[mi], bf, zf4, 0, 0, 0);
    // h = gelu(acc1 + b1); write to Hsm[c_local][t]  (t = mi*16 + kc*4 + r)
    #pragma unroll
    for (int mi = 0; mi < 4; ++mi) {
      const float g0 = gelu_f(acc1[mi][0] + b1v[mi][0]);
      const float g1 = gelu_f(acc1[mi][1] + b1v[mi][1]);
      const float g2 = gelu_f(acc1[mi][2] + b1v[mi][2]);
      const float g3 = gelu_f(acc1[mi][3] + b1v[mi][3]);
      unsigned* hp = (unsigned*)(hs + lr * 144 + (mi * 16 + kc * 4) * 2);
      hp[0] = pk2(g0, g1);
      hp[1] = pk2(g2, g3);
    }
    // GEMM2: mjem rows j (pad 32), cols c-block, K = 64 over t
    f32x4 acc2[2] = {zf4, zf4};
    #pragma unroll
    for (int kk = 0; kk < 2; ++kk) {
      const bf16x8 hb = *(const bf16x8*)(hs + lr * 144 + kk * 64 + kc * 16);
      #pragma unroll
      for (int mi = 0; mi < 2; ++mi)
        acc2[mi] = __builtin_amdgcn_mfma_f32_16x16x32_bf16(a2[mi][kk], hb, acc2[mi], 0, 0, 0);
    }
    __hip_bfloat16* mp = mjem + (size_t)b * J_ * C_ + (c0 + lr);
    #pragma unroll
    for (int r = 0; r < 4; ++r)
      mp[(kc * 4 + r) * C_] = f2b(acc2[0][r] + b2v[r]);       // j = kc*4+r in 0..15
    if (kc == 0) mp[16 * C_] = f2b(acc2[1][0] + b2v16);       // j = 16
  }
}

// ---------------- fuse: pos-conv + sum + GN + GELU + residual + LN2 ----------------
__global__ __launch_bounds__(512) void fuse_kernel(
    const float* __restrict__ x, const __hip_bfloat16* __restrict__ xnT,
    const __hip_bfloat16* __restrict__ g1o, const __hip_bfloat16* __restrict__ projo,
    const __hip_bfloat16* __restrict__ mjem,
    const float* __restrict__ posw, const float* __restrict__ posb,
    const float* __restrict__ gnfg, const float* __restrict__ gnfb,
    const float* __restrict__ n2g, const float* __restrict__ n2b,
    __hip_bfloat16* __restrict__ resch, __hip_bfloat16* __restrict__ xn2) {
  const int b = blockIdx.x, tid = threadIdx.x;
  __shared__ float xcl[J_][C_];
  __shared__ float gstat[16][2];
  __shared__ float lnst[J_][2];
  if (tid < 32) gstat[tid >> 1][tid & 1] = 0.f;
  __syncthreads();
  const int c = tid;
  float fz[J_];
  if (c < C_) {
    float xnv[J_];
    const __hip_bfloat16* xp = xnT + (size_t)b * J_ * C_ + c;
    #pragma unroll
    for (int j = 0; j < J_; ++j) xnv[j] = b2f(xp[j * C_]);
    float pw[9];
    #pragma unroll
    for (int t = 0; t < 9; ++t) pw[t] = posw[c * 9 + t];
    const float pb = posb[c];
    const __hip_bfloat16* pj = projo + (size_t)b * J_ * C_ + c;
    const __hip_bfloat16* mp = mjem + (size_t)b * J_ * C_ + c;
    const __hip_bfloat16* gp = g1o + (size_t)b * J_ * C_ + c;
    float s = 0.f, sqs = 0.f;
    #pragma unroll
    for (int j = 0; j < J_; ++j) {
      float pos = pb;
      #pragma unroll
      for (int t = 0; t < 9; ++t) {
        const int jj = j - 4 + t;
        if (jj >= 0 && jj < J_) pos += xnv[jj] * pw[t];
      }
      const float f = b2f(pj[j * C_]) + pos + b2f(gp[j * C_]) + b2f(mp[j * C_]);
      fz[j] = f; s += f; sqs += f * f;
    }
    atomicAdd(&gstat[c / 30][0], s);
    atomicAdd(&gstat[c / 30][1], sqs);
  }
  __syncthreads();
  if (c < C_) {
    const float mu = gstat[c / 30][0] * (1.f / 510.f);
    const float var = gstat[c / 30][1] * (1.f / 510.f) - mu * mu;
    const float rs = rsqrtf(var + EPSF);
    const float sc = gnfg[c], of = gnfb[c];
    const float* xr = x + (size_t)b * J_ * C_ + c;
    __hip_bfloat16* rp = resch + (size_t)b * J_ * C_ + c;
    #pragma unroll
    for (int j = 0; j < J_; ++j) {
      const float xcv = xr[j * C_] + gelu_f((fz[j] - mu) * rs * sc + of);
      xcl[j][c] = xcv;
      rp[j * C_] = f2b(xcv);
    }
  }
  __syncthreads();
  const int wid = tid >> 6, lane = tid & 63;
  for (int j = wid; j < J_; j += 8) {
    float ls = 0.f, lq = 0.f;
    for (int cc = lane; cc < C_; cc += 64) { const float v = xcl[j][cc]; ls += v; lq += v * v; }
    #pragma unroll
    for (int off = 32; off > 0; off >>= 1) { ls += __shfl_xor(ls, off); lq += __shfl_xor(lq, off); }
    if (lane == 0) {
      const float mu = ls * (1.f / C_);
      const float var = lq * (1.f / C_) - mu * mu;
      lnst[j][0] = mu; lnst[j][1] = rsqrtf(var + EPSF);
    }
  }
  __syncthreads();
  if (c < C_) {
    const float sc = n2g[c], of = n2b[c];
    __hip_bfloat16* xp2 = xn2 + (size_t)b * J_ * C_ + c;
    #pragma unroll
    for (int j = 0; j < J_; ++j)
      xp2[j * C_] = f2b((xcl[j][c] - lnst[j][0]) * lnst[j][1] * sc + of);
  }
}

extern "C" void kernel_launch(void* const* d_in, const int* in_sizes, int n_in,
                              void* d_out, int out_size, void* d_ws, size_t ws_size,
                              hipStream_t stream) {
  const float* x      = (const float*)d_in[0];
  const float* adj    = (const float*)d_in[1];
  const float* n1g    = (const float*)d_in[2];
  const float* n1b    = (const float*)d_in[3];
  const float* gcn1_w = (const float*)d_in[4];
  const float* gcn1_b = (const float*)d_in[5];
  const float* dw_w   = (const float*)d_in[6];
  const float* dw_b   = (const float*)d_in[7];
  const float* dwgn_g = (const float*)d_in[8];
  const float* dwgn_b = (const float*)d_in[9];
  const float* m1w1   = (const float*)d_in[10];
  const float* m1b1   = (const float*)d_in[11];
  const float* m1w2   = (const float*)d_in[12];
  const float* m1b2   = (const float*)d_in[13];
  const float* qkv_w  = (const float*)d_in[14];
  const float* qkv_b  = (const float*)d_in[15];
  const float* proj_w = (const float*)d_in[16];
  const float* proj_b = (const float*)d_in[17];
  const float* pos_w  = (const float*)d_in[18];
  const float* pos_b  = (const float*)d_in[19];
  const float* gnf_g  = (const float*)d_in[20];
  const float* gnf_b  = (const float*)d_in[21];
  const float* n2g    = (const float*)d_in[22];
  const float* n2b    = (const float*)d_in[23];
  const float* gcn2_w = (const float*)d_in[24];
  const float* gcn2_b = (const float*)d_in[25];
  const float* m2w1   = (const float*)d_in[26];
  const float* m2b1   = (const float*)d_in[27];
  const float* m2w2   = (const float*)d_in[28];
  const float* m2b2   = (const float*)d_in[29];
  float* out = (float*)d_out;
  char* ws = (char*)d_ws;
  (void)in_sizes; (void)n_in; (void)out_size;

  auto a256 = [](size_t b) { return (b + 255) & ~(size_t)255; };
  const size_t wbytes = 3 * a256((size_t)C3_ * C_ * 2) + a256((size_t)C_ * C_ * 2) +
                        a256((size_t)CH_ * C_ * 2) + a256((size_t)C_ * CH_ * 2);
  int nch = 16;
  for (int cand : {1, 2, 4, 8, 16}) {
    const size_t Mcb = (size_t)(B_ / cand) * J_;
    const size_t fp = wbytes + a256(Mcb * C3_ * 2) + 6 * a256(Mcb * C_ * 2);
    if (fp <= ws_size) { nch = cand; break; }
  }
  const int Bc = B_ / nch;
  const int Mc = Bc * J_;

  size_t off = 0;
  auto alloc = [&](size_t bytes) { char* p = ws + off; off += a256(bytes); return p; };
  // weight arena: 6 contiguous segments in cvt_all ladder order (alloc order matters!)
  __hip_bfloat16* w_qkv = (__hip_bfloat16*)alloc((size_t)C3_ * C_ * 2);
  __hip_bfloat16* w_g1  = (__hip_bfloat16*)alloc((size_t)C3_ * C_ * 2);
  __hip_bfloat16* w_g2  = (__hip_bfloat16*)alloc((size_t)C3_ * C_ * 2);
  __hip_bfloat16* w_pr  = (__hip_bfloat16*)alloc((size_t)C_ * C_ * 2);
  __hip_bfloat16* w_21  = (__hip_bfloat16*)alloc((size_t)CH_ * C_ * 2);
  __hip_bfloat16* w_22  = (__hip_bfloat16*)alloc((size_t)C_ * CH_ * 2);
  __hip_bfloat16* BIG   = (__hip_bfloat16*)alloc((size_t)Mc * C3_ * 2);  // qkv -> y1 -> y2 -> hbuf
  __hip_bfloat16* xnT   = (__hip_bfloat16*)alloc((size_t)Mc * C_ * 2);
  __hip_bfloat16* attno = (__hip_bfloat16*)alloc((size_t)Mc * C_ * 2);   // -> xn2
  __hip_bfloat16* projo = (__hip_bfloat16*)alloc((size_t)Mc * C_ * 2);
  __hip_bfloat16* mjem  = (__hip_bfloat16*)alloc((size_t)Mc * C_ * 2);
  __hip_bfloat16* g1o   = (__hip_bfloat16*)alloc((size_t)Mc * C_ * 2);   // -> g2o
  __hip_bfloat16* resch = (__hip_bfloat16*)alloc((size_t)Mc * C_ * 2);
  __hip_bfloat16* xn2   = attno;
  __hip_bfloat16* g2o   = g1o;
  __hip_bfloat16* hbuf  = BIG;

  cvt_all_kernel<<<3150, 256, 0, stream>>>(qkv_w, gcn1_w, gcn2_w, proj_w, m2w1, m2w2, w_qkv);

  for (int ci = 0; ci < nch; ++ci) {
    const float* xc = x + (size_t)ci * Bc * J_ * C_;
    float* outc = out + (size_t)ci * Bc * J_ * C_;
    ln1_kernel<<<(Bc * C_ + 255) / 256, 256, 0, stream>>>(xc, n1g, n1b, xnT, Bc * C_);
    gemm_lds<C_, 0><<<dim3(Mc / 128, C3_ / 96), 256, 0, stream>>>(xnT, w_qkv, qkv_b, BIG, C3_, nullptr, nullptr, nullptr);
    attn_kernel<<<Bc, 256, 0, stream>>>(BIG, attno);
    gemm_lds<C_, 0><<<dim3(Mc / 128, C3_ / 96), 256, 0, stream>>>(xnT, w_g1, gcn1_b, BIG, C3_, nullptr, nullptr, nullptr);
    gcn_contract_kernel<<<Bc, 512, 0, stream>>>(BIG, adj, g1o);
    gemm_lds<C_, 0><<<dim3(Mc / 128, C_ / 96), 256, 0, stream>>>(attno, w_pr, proj_b, projo, C_, nullptr, nullptr, nullptr);
    dwmlp_kernel<<<Bc, 512, 0, stream>>>(xnT, dw_w, dw_b, dwgn_g, dwgn_b, m1w1, m1b1, m1w2, m1b2, mjem);
    fuse_kernel<<<Bc, 512, 0, stream>>>(xc, xnT, g1o, projo, mjem, pos_w, pos_b,
                                        gnf_g, gnf_b, n2g, n2b, resch, xn2);
    gemm_lds<C_, 0><<<dim3(Mc / 128, C3_ / 96), 256, 0, stream>>>(xn2, w_g2, gcn2_b, BIG, C3_, nullptr, nullptr, nullptr);
    gcn_contract_kernel<<<Bc, 512, 0, stream>>>(BIG, adj, g2o);
    gemm_lds<C_, 1><<<dim3(Mc / 128, CH_ / 96), 256, 0, stream>>>(xn2, w_21, m2b1, hbuf, CH_, nullptr, nullptr, nullptr);
    gemm_lds<CH_, 2><<<dim3(Mc / 128, C_ / 96), 256, 0, stream>>>(hbuf, w_22, m2b2, nullptr, C_, resch, g2o, outc);
  }
}